// Round 2
// baseline (298.914 us; speedup 1.0000x reference)
//
#include <hip/hip_runtime.h>
#include <math.h>

typedef __bf16 bf16;
typedef __bf16 bf16x4 __attribute__((ext_vector_type(4)));
typedef __bf16 bf16x8 __attribute__((ext_vector_type(8)));
typedef float  f32x4  __attribute__((ext_vector_type(4)));
typedef unsigned short u16;

#define MFMA16(a, b, c) __builtin_amdgcn_mfma_f32_16x16x32_bf16((a), (b), (c), 0, 0, 0)

constexpr int Bz    = 4;
constexpr int Ts    = 2048;
constexpr int DM    = 1024;
constexpr int NH    = 16;
constexpr int HS    = 64;
constexpr int MROWS = Bz * Ts;   // 8192
constexpr int NQKV  = 3 * DM;    // 3072

// float4-chunk counts for the fused convert kernel
constexpr int NX4  = MROWS * DM / 4;    // 2097152
constexpr int NW14 = NQKV * DM / 4;     //  786432
constexpr int NW24 = DM * DM / 4;       //  262144

// 0.125 (1/sqrt(64)) * log2(e): folded into Q at the QKV-GEMM epilogue.
#define QSCALE 0.18033688011112042f

__device__ __forceinline__ unsigned int pack2(bf16 lo, bf16 hi) {
    return ((unsigned int)__builtin_bit_cast(u16, hi) << 16) |
            (unsigned int)__builtin_bit_cast(u16, lo);
}

// ---------------------------------------------------------------------------
__device__ __forceinline__ void load_lds16(const bf16* g, bf16* l) {
    __builtin_amdgcn_global_load_lds(
        (__attribute__((address_space(1))) void*)(g),
        (__attribute__((address_space(3))) void*)(l), 16, 0, 0);
}

// ---------------------------------------------------------------------------
// Fused fp32->bf16 conversion for x, W_qkv, W_proj in one launch.
__global__ __launch_bounds__(256) void cvt3_kernel(const float* __restrict__ x,   bf16* __restrict__ xb,
                                                   const float* __restrict__ w1,  bf16* __restrict__ w1b,
                                                   const float* __restrict__ w2,  bf16* __restrict__ w2b)
{
    int i = blockIdx.x * 256 + threadIdx.x;
    const float* in; bf16* out;
    if (i < NX4)              { in = x;  out = xb;  }
    else if (i < NX4 + NW14)  { in = w1; out = w1b; i -= NX4; }
    else                      { in = w2; out = w2b; i -= NX4 + NW14; }
    float4 v = ((const float4*)in)[i];
    bf16x4 o = { (bf16)v.x, (bf16)v.y, (bf16)v.z, (bf16)v.w };
    ((bf16x4*)out)[i] = o;
}

// ---------------------------------------------------------------------------
// C = A * B^T + bias.  128x128 tile, BK=32, 256 threads (m97 structure).
// Retained for the proj GEMM (known-good).
template <int OUT_BF16>
__global__ __launch_bounds__(256) void gemm_bt(const bf16* __restrict__ A,
                                               const bf16* __restrict__ Bw,
                                               const float* __restrict__ bias,
                                               void* __restrict__ Cout,
                                               int M, int N, int K,
                                               float qscale, int qcols)
{
    __shared__ __align__(16) bf16 As[128 * 32];
    __shared__ __align__(16) bf16 Bs[128 * 32];

    const int tid  = threadIdx.x;
    const int wave = tid >> 6, lane = tid & 63;
    const int quad = lane >> 4, l16 = lane & 15;
    const int wm = (wave >> 1) * 64, wn = (wave & 1) * 64;
    const int m0 = blockIdx.x * 128, n0 = blockIdx.y * 128;

    f32x4 acc[4][4] = {};

    const int c0 = tid, c1 = tid + 256;
    const bf16* gA0 = A  + (size_t)(m0 + (c0 >> 2)) * K + (c0 & 3) * 8;
    const bf16* gA1 = A  + (size_t)(m0 + (c1 >> 2)) * K + (c1 & 3) * 8;
    const bf16* gB0 = Bw + (size_t)(n0 + (c0 >> 2)) * K + (c0 & 3) * 8;
    const bf16* gB1 = Bw + (size_t)(n0 + (c1 >> 2)) * K + (c1 & 3) * 8;
    bf16* lA0 = As + c0 * 8;  bf16* lA1 = As + c1 * 8;
    bf16* lB0 = Bs + c0 * 8;  bf16* lB1 = Bs + c1 * 8;

    for (int kb = 0; kb < K; kb += 32) {
        if (kb) __syncthreads();
        load_lds16(gA0 + kb, lA0);
        load_lds16(gA1 + kb, lA1);
        load_lds16(gB0 + kb, lB0);
        load_lds16(gB1 + kb, lB1);
        __syncthreads();

        bf16x8 af[4], bfr[4];
#pragma unroll
        for (int mt = 0; mt < 4; ++mt)
            af[mt] = *(const bf16x8*)(As + (wm + mt * 16 + l16) * 32 + quad * 8);
#pragma unroll
        for (int nt = 0; nt < 4; ++nt)
            bfr[nt] = *(const bf16x8*)(Bs + (wn + nt * 16 + l16) * 32 + quad * 8);
#pragma unroll
        for (int mt = 0; mt < 4; ++mt)
#pragma unroll
            for (int nt = 0; nt < 4; ++nt)
                acc[mt][nt] = MFMA16(af[mt], bfr[nt], acc[mt][nt]);
    }

#pragma unroll
    for (int mt = 0; mt < 4; ++mt)
#pragma unroll
        for (int nt = 0; nt < 4; ++nt) {
            const int row = m0 + wm + mt * 16 + quad * 4;
            const int col = n0 + wn + nt * 16 + l16;
            const float bc = bias[col];
            const float sc = (col < qcols) ? qscale : 1.0f;
#pragma unroll
            for (int r = 0; r < 4; ++r) {
                const float v = (acc[mt][nt][r] + bc) * sc;
                if (OUT_BF16) ((bf16*)Cout)[(size_t)(row + r) * N + col] = (bf16)v;
                else          ((float*)Cout)[(size_t)(row + r) * N + col] = v;
            }
        }
}

// ---------------------------------------------------------------------------
// QKV GEMM v2: faithful 256x256 / BK=64 / 8-wave 4-phase-per-K-tile pipeline
// with PROVEN-consistent half-tile staging ledger.
//
// Stage granularity: half-tile = 128 rows x 64 K of one matrix (2 loads/thr).
// Stage sequence during tile kt:  ph1: A-mh1(kt+1)   [parity kt+1]
//                                 ph2: B-nh0(kt+2)   [parity kt  ]
//                                 ph3: B-nh1(kt+2)   [parity kt  ]
//                                 ph4: A-mh0(kt+2) + vmcnt(6)
// Ledger @ ph4(T-1) checkpoint: 3 newest halves (6 loads) all belong to T+1,
// so ALL of tile T is landed before its first read.  Slab-death vs same-parity
// stage-write: B slab read only in ph1 (stages land ph2/ph3 after barrier);
// A slab read through ph3 (stage lands ph4).  Register reads: 12/4/8/0.
//
// st_16x32 LDS swizzle: stored chunk c = k16 ^ (((row>>2)&1)<<1), applied as
// inverse-permuted GLOBAL source (linear global_load_lds dest) + swizzled
// ds_read address (rule #21: both-sides involution).
constexpr int GM  = MROWS;      // 8192
constexpr int GN  = NQKV;       // 3072
constexpr int GK  = DM;         // 1024
constexpr int NBX = GM / 256;   // 32
constexpr int NBY = GN / 256;   // 12
constexpr int NWG = NBX * NBY;  // 384 (div by 8 -> bijective XCD swizzle)
constexpr int NKT = GK / 64;    // 16 K-tiles

__global__ __launch_bounds__(512, 2) void gemm256_qkv(const bf16* __restrict__ A,
                                                      const bf16* __restrict__ Bw,
                                                      const float* __restrict__ bias,
                                                      bf16* __restrict__ C)
{
    __shared__ __align__(16) bf16 AS[2][2][128 * 64];   // [parity][mhalf] 64 KiB
    __shared__ __align__(16) bf16 BS[2][2][128 * 64];   // [parity][nhalf] 64 KiB

    const int tid  = threadIdx.x;
    const int wave = tid >> 6, lane = tid & 63;
    const int quad = lane >> 4, l16 = lane & 15;
    const int wmh  = wave >> 2;              // M-half slab index (wm = wmh*128)
    const int wnq  = wave & 3;               // wn = wnq*64
    const int wnh  = wnq >> 1;               // N-half slab index
    const int wn_in = (wnq & 1) * 64;        // row offset inside N-half slab

    // bijective XCD-aware remap (384 % 8 == 0)
    const int id  = blockIdx.x;
    const int swz = (id & 7) * (NWG / 8) + (id >> 3);
    const int m0  = (swz % NBX) * 256;
    const int n0  = (swz / NBX) * 256;

    // ---- staging mapping: linear LDS dest (tid*16B), inverse-swizzled src.
    // dest byte o = tid*16 (+8192 for 2nd load): row = o>>7, stored chunk = o>>4 & 7.
    // logical k16 = chunk ^ (((row>>2)&1)<<1);  row bit2 = (tid>>5)&1 (both loads).
    const int r0  = tid >> 3;                           // 0..63 (2nd load: +64)
    const int lk0 = (tid & 7) ^ (((tid >> 5) & 1) << 1);
    const bf16* Agb = A  + (size_t)(m0 + r0) * GK + lk0 * 8;
    const bf16* Bgb = Bw + (size_t)(n0 + r0) * GK + lk0 * 8;

    // ---- frag-read addressing (swizzled): elem = row*64 + ks*32 + (quad^axor)*8
    const int axor = ((l16 >> 2) & 1) << 1;
    const int qsw  = (quad ^ axor) * 8;
    const int aoff = l16 * 64 + qsw;
    const int boff = (wn_in + l16) * 64 + qsw;

    f32x4 acc[8][4] = {};
    bf16x8 ar[4], aq0[4], aq1[4], bb[2][4];

#define STAGE_A(pp, hh, tt) { const bf16* s_ = Agb + (size_t)(hh) * 128 * GK + (tt) * 64; \
        bf16* d_ = &AS[pp][hh][0] + tid * 8;                                              \
        load_lds16(s_, d_); load_lds16(s_ + (size_t)64 * GK, d_ + 4096); }
#define STAGE_B(pp, hh, tt) { const bf16* s_ = Bgb + (size_t)(hh) * 128 * GK + (tt) * 64; \
        bf16* d_ = &BS[pp][hh][0] + tid * 8;                                              \
        load_lds16(s_, d_); load_lds16(s_ + (size_t)64 * GK, d_ + 4096); }
#define BAR()  __builtin_amdgcn_s_barrier()
#define VMW6() __asm__ volatile("s_waitcnt vmcnt(6)" ::: "memory")
#define LD_PH1(pp) { const bf16* bp_ = &BS[pp][wnh][0] + boff;                  \
        const bf16* ap_ = &AS[pp][wmh][0] + aoff;                               \
        _Pragma("unroll") for (int nf = 0; nf < 4; ++nf)                        \
            bb[0][nf] = *(const bf16x8*)(bp_ + nf * 1024);                      \
        _Pragma("unroll") for (int nf = 0; nf < 4; ++nf)                        \
            bb[1][nf] = *(const bf16x8*)(bp_ + nf * 1024 + 32);                 \
        _Pragma("unroll") for (int mf = 0; mf < 4; ++mf)                        \
            ar[mf] = *(const bf16x8*)(ap_ + mf * 1024); }
#define LD_PH2(pp) { const bf16* ap_ = &AS[pp][wmh][0] + aoff + 32;             \
        _Pragma("unroll") for (int mf = 0; mf < 4; ++mf)                        \
            ar[mf] = *(const bf16x8*)(ap_ + mf * 1024); }
#define LD_PH3(pp) { const bf16* ap_ = &AS[pp][wmh][0] + aoff + 4096;           \
        _Pragma("unroll") for (int mf = 0; mf < 4; ++mf)                        \
            aq0[mf] = *(const bf16x8*)(ap_ + mf * 1024);                        \
        _Pragma("unroll") for (int mf = 0; mf < 4; ++mf)                        \
            aq1[mf] = *(const bf16x8*)(ap_ + mf * 1024 + 32); }
#define MMA(base, AF, ks) { __builtin_amdgcn_s_setprio(1);                      \
        _Pragma("unroll") for (int mf = 0; mf < 4; ++mf)                        \
        _Pragma("unroll") for (int nf = 0; nf < 4; ++nf)                        \
            acc[(base) + mf][nf] = MFMA16(AF[mf], bb[ks][nf], acc[(base) + mf][nf]); \
        __builtin_amdgcn_s_setprio(0); }

    // ---- prologue: tile0 (4 halves) + tile1 first 3 halves; vmcnt(6) -> tile0 landed
    STAGE_B(0, 0, 0); STAGE_B(0, 1, 0); STAGE_A(0, 0, 0); STAGE_A(0, 1, 0);
    STAGE_B(1, 0, 1); STAGE_B(1, 1, 1); STAGE_A(1, 0, 1);
    VMW6();
    BAR();

    for (int kt = 0; kt < NKT; ++kt) {
        const int par = kt & 1, np = par ^ 1;
        const int t1 = (kt + 1 < NKT) ? kt + 1 : NKT - 1;
        const int t2 = (kt + 2 < NKT) ? kt + 2 : NKT - 1;
        // ---- phase 1: Q(g0,ks0); 12 ds_reads; stage A-mh1(kt+1)
        LD_PH1(par);
        STAGE_A(np, 1, t1);
        BAR(); MMA(0, ar, 0); BAR();
        // ---- phase 2: Q(g0,ks1); 4 ds_reads; stage B-nh0(kt+2)
        LD_PH2(par);
        STAGE_B(par, 0, t2);
        BAR(); MMA(0, ar, 1); BAR();
        // ---- phase 3: Q(g1,ks0); 8 ds_reads; stage B-nh1(kt+2)
        LD_PH3(par);
        STAGE_B(par, 1, t2);
        BAR(); MMA(4, aq0, 0); BAR();
        // ---- phase 4: Q(g1,ks1); stage A-mh0(kt+2); vmcnt(6)
        STAGE_A(par, 0, t2);
        VMW6();
        BAR(); MMA(4, aq1, 1); BAR();
    }

#undef STAGE_A
#undef STAGE_B
#undef BAR
#undef VMW6
#undef LD_PH1
#undef LD_PH2
#undef LD_PH3
#undef MMA

    // ---- epilogue: bias + Q pre-scale (cols < DM), bf16 store
#pragma unroll
    for (int a = 0; a < 8; ++a)
#pragma unroll
        for (int nf = 0; nf < 4; ++nf) {
            const int row = m0 + wmh * 128 + a * 16 + quad * 4;
            const int col = n0 + wnq * 64 + nf * 16 + l16;
            const float bc = bias[col];
            const float sc = (col < DM) ? QSCALE : 1.0f;
#pragma unroll
            for (int r = 0; r < 4; ++r) {
                const float v = (acc[a][nf][r] + bc) * sc;
                C[(size_t)(row + r) * GN + col] = (bf16)v;
            }
        }
}

// ---------------------------------------------------------------------------
// Vt key-block swizzle keyed on d>>3: conflict-minimal for the packed b32
// transpose-write and the b128 PV read. (round-5-verified)
__device__ __forceinline__ int vswz(int d) { return ((d >> 3) & 7) << 3; }

// Flash attention, S^T formulation — EXACT round-5 configuration.
__global__ __launch_bounds__(256) void attn_kernel(const bf16* __restrict__ qkv,
                                                   bf16* __restrict__ y)
{
    __shared__ __align__(16) bf16 Ks[64][72];      // [key][d]
    __shared__ __align__(16) bf16 Vt[64][72];      // [d][key ^ vswz(d)]
    __shared__ __align__(16) bf16 Ps[4][16][72];   // per-wave [q=l16][key]

    const int p = blockIdx.x, h = blockIdx.y, b = blockIdx.z;
    const int tid  = threadIdx.x;
    const int wave = tid >> 6, lane = tid & 63;
    const int quad = lane >> 4, l16 = lane & 15;

    const bf16* kbase = qkv + (size_t)(b * Ts) * NQKV + DM     + h * HS;
    const bf16* vbase = qkv + (size_t)(b * Ts) * NQKV + 2 * DM + h * HS;

    const int dg = tid & 7, kp = tid >> 3;   // V staging mapping
    const int k0 = 2 * kp;

    for (int phase = 0; phase < 2; ++phase) {
        const int qt = phase ? (31 - p) : p;
        const int qw = qt * 64 + wave * 16;
        const int q_abs = qw + l16;

        const bf16* qrow = qkv + (size_t)(b * Ts + qw + l16) * NQKV + h * HS;
        const bf16x8 qf0 = *(const bf16x8*)(qrow + quad * 8);
        const bf16x8 qf1 = *(const bf16x8*)(qrow + 32 + quad * 8);

        f32x4 o[4] = {};            // O^T[d = dt*16 + quad*4 + r][q = l16]
        float m_run = -1e30f, l_run = 0.f;

        auto iter = [&](int kt, bool masked) {
            __syncthreads();   // prior iter's Ks/Vt reads complete

            // ---- stage K [64x64] natural, b128 writes
            {
                int e = tid * 8;
#pragma unroll
                for (int rr = 0; rr < 2; ++rr, e += 2048) {
                    const int key = e >> 6, c = e & 63;
                    bf16x8 kv = *(const bf16x8*)(kbase + (size_t)(kt * 64 + key) * NQKV + c);
                    *(bf16x8*)&Ks[key][c] = kv;
                }
            }
            // ---- stage V transposed: key-pair packed b32 writes
            {
                const bf16x8 v0 = *(const bf16x8*)(vbase + (size_t)(kt * 64 + k0)     * NQKV + dg * 8);
                const bf16x8 v1 = *(const bf16x8*)(vbase + (size_t)(kt * 64 + k0 + 1) * NQKV + dg * 8);
#pragma unroll
                for (int j = 0; j < 8; ++j) {
                    const int d = dg * 8 + j;
                    *(unsigned int*)&Vt[d][k0 ^ vswz(d)] = pack2(v0[j], v1[j]);
                }
            }
            __syncthreads();

            // ---- S^T (log2 domain, scale pre-folded into Q)
            f32x4 s[4];
#pragma unroll
            for (int sub = 0; sub < 4; ++sub) {
                bf16x8 kf0 = *(const bf16x8*)&Ks[sub * 16 + l16][quad * 8];
                bf16x8 kf1 = *(const bf16x8*)&Ks[sub * 16 + l16][32 + quad * 8];
                f32x4 z = {};
                z = MFMA16(kf0, qf0, z);
                z = MFMA16(kf1, qf1, z);
                s[sub] = z;
            }

            // ---- causal mask: only the diagonal tile needs it
            if (masked) {
#pragma unroll
                for (int sub = 0; sub < 4; ++sub) {
                    const int kb = kt * 64 + sub * 16 + quad * 4;
#pragma unroll
                    for (int r = 0; r < 4; ++r)
                        if (kb + r > q_abs) s[sub][r] = -1e30f;
                }
            }

            // ---- online softmax (log2 domain): balanced trees + 2 shfls
            float mA = fmaxf(fmaxf(s[0][0], s[0][1]), fmaxf(s[0][2], s[0][3]));
            float mB = fmaxf(fmaxf(s[1][0], s[1][1]), fmaxf(s[1][2], s[1][3]));
            float mC = fmaxf(fmaxf(s[2][0], s[2][1]), fmaxf(s[2][2], s[2][3]));
            float mD = fmaxf(fmaxf(s[3][0], s[3][1]), fmaxf(s[3][2], s[3][3]));
            float mx = fmaxf(fmaxf(mA, mB), fmaxf(mC, mD));
            mx = fmaxf(mx, __shfl_xor(mx, 16, 64));
            mx = fmaxf(mx, __shfl_xor(mx, 32, 64));
            const float mnew  = fmaxf(m_run, mx);
            const float alpha = __builtin_amdgcn_exp2f(m_run - mnew);
#pragma unroll
            for (int sub = 0; sub < 4; ++sub)
#pragma unroll
                for (int r = 0; r < 4; ++r)
                    s[sub][r] = __builtin_amdgcn_exp2f(s[sub][r] - mnew);
            float t0 = (s[0][0] + s[0][1]) + (s[0][2] + s[0][3]);
            float t1 = (s[1][0] + s[1][1]) + (s[1][2] + s[1][3]);
            float t2 = (s[2][0] + s[2][1]) + (s[2][2] + s[2][3]);
            float t3 = (s[3][0] + s[3][1]) + (s[3][2] + s[3][3]);
            float ls = (t0 + t1) + (t2 + t3);
            ls += __shfl_xor(ls, 16, 64);
            ls += __shfl_xor(ls, 32, 64);
            l_run = l_run * alpha + ls;
            m_run = mnew;
#pragma unroll
            for (int dt = 0; dt < 4; ++dt)
#pragma unroll
                for (int r = 0; r < 4; ++r) o[dt][r] *= alpha;

            // ---- P -> per-wave LDS [q=l16][key], packed key-pair b32 writes
#pragma unroll
            for (int sub = 0; sub < 4; ++sub) {
                const int kc = sub * 16 + quad * 4;
                *(unsigned int*)&Ps[wave][l16][kc]     = pack2((bf16)s[sub][0], (bf16)s[sub][1]);
                *(unsigned int*)&Ps[wave][l16][kc + 2] = pack2((bf16)s[sub][2], (bf16)s[sub][3]);
            }
            __asm__ volatile("" ::: "memory");   // keep reads below writes

            bf16x8 pb0 = *(const bf16x8*)&Ps[wave][l16][quad * 8];
            bf16x8 pb1 = *(const bf16x8*)&Ps[wave][l16][32 + quad * 8];

            // ---- O^T += V^T * P
#pragma unroll
            for (int kb = 0; kb < 2; ++kb) {
                const int kcol = kb * 32 + quad * 8;
#pragma unroll
                for (int dt = 0; dt < 4; ++dt) {
                    const int d = dt * 16 + l16;
                    bf16x8 vf = *(const bf16x8*)&Vt[d][kcol ^ vswz(d)];
                    o[dt] = MFMA16(vf, kb ? pb1 : pb0, o[dt]);
                }
            }
        };

        for (int kt = 0; kt < qt; ++kt) iter(kt, false);
        iter(qt, true);

        // ---- normalize + write
        const float inv = 1.f / l_run;
        bf16* yrow = y + (size_t)(b * Ts + qw + l16) * DM + h * HS;
#pragma unroll
        for (int dt = 0; dt < 4; ++dt) {
            bf16x4 ov;
#pragma unroll
            for (int r = 0; r < 4; ++r) ov[r] = (bf16)(o[dt][r] * inv);
            *(bf16x4*)(yrow + dt * 16 + quad * 4) = ov;
        }
    }
}

// ---------------------------------------------------------------------------
extern "C" void kernel_launch(void* const* d_in, const int* in_sizes, int n_in,
                              void* d_out, int out_size, void* d_ws, size_t ws_size,
                              hipStream_t stream)
{
    const float* x     = (const float*)d_in[0];
    const float* Wqkv  = (const float*)d_in[1];
    const float* bqkv  = (const float*)d_in[2];
    const float* Wproj = (const float*)d_in[3];
    const float* bproj = (const float*)d_in[4];

    char* ws = (char*)d_ws;
    bf16* xb     = (bf16*)ws;  ws += (size_t)MROWS * DM * 2;
    bf16* wqkvb  = (bf16*)ws;  ws += (size_t)NQKV * DM * 2;
    bf16* wprojb = (bf16*)ws;  ws += (size_t)DM * DM * 2;
    bf16* qkvb   = (bf16*)ws;  ws += (size_t)MROWS * NQKV * 2;
    bf16* yb     = (bf16*)ws;

    cvt3_kernel<<<(NX4 + NW14 + NW24) / 256, 256, 0, stream>>>(
        x, xb, Wqkv, wqkvb, Wproj, wprojb);

    gemm256_qkv<<<dim3(NWG), 512, 0, stream>>>(xb, wqkvb, bqkv, qkvb);

    attn_kernel<<<dim3(16, NH, Bz), 256, 0, stream>>>(qkvb, yb);

    gemm_bt<0><<<dim3(MROWS / 128, DM / 128), 256, 0, stream>>>(
        yb, wprojb, bproj, d_out, MROWS, DM, DM, 1.0f, 0);
}

// Round 3
// 274.415 us; speedup vs baseline: 1.0893x; 1.0893x over previous
//
#include <hip/hip_runtime.h>
#include <math.h>

typedef __bf16 bf16;
typedef __bf16 bf16x4 __attribute__((ext_vector_type(4)));
typedef __bf16 bf16x8 __attribute__((ext_vector_type(8)));
typedef float  f32x4  __attribute__((ext_vector_type(4)));
typedef unsigned short u16;

#define MFMA16(a, b, c) __builtin_amdgcn_mfma_f32_16x16x32_bf16((a), (b), (c), 0, 0, 0)

constexpr int Bz    = 4;
constexpr int Ts    = 2048;
constexpr int DM    = 1024;
constexpr int NH    = 16;
constexpr int HS    = 64;
constexpr int MROWS = Bz * Ts;   // 8192
constexpr int NQKV  = 3 * DM;    // 3072

// float4-chunk counts for the fused convert kernel
constexpr int NX4  = MROWS * DM / 4;    // 2097152
constexpr int NW14 = NQKV * DM / 4;     //  786432
constexpr int NW24 = DM * DM / 4;       //  262144

// 0.125 (1/sqrt(64)) * log2(e): folded into Q at the QKV-GEMM epilogue.
#define QSCALE 0.18033688011112042f

__device__ __forceinline__ unsigned int pack2(bf16 lo, bf16 hi) {
    return ((unsigned int)__builtin_bit_cast(u16, hi) << 16) |
            (unsigned int)__builtin_bit_cast(u16, lo);
}

// ---------------------------------------------------------------------------
__device__ __forceinline__ void load_lds16(const bf16* g, bf16* l) {
    __builtin_amdgcn_global_load_lds(
        (__attribute__((address_space(1))) void*)(g),
        (__attribute__((address_space(3))) void*)(l), 16, 0, 0);
}

// ---------------------------------------------------------------------------
// Fused fp32->bf16 conversion for x, W_qkv, W_proj in one launch.
// All three ranges are multiples of 256 -> branch is block-uniform.
__global__ __launch_bounds__(256) void cvt3_kernel(const float* __restrict__ x,   bf16* __restrict__ xb,
                                                   const float* __restrict__ w1,  bf16* __restrict__ w1b,
                                                   const float* __restrict__ w2,  bf16* __restrict__ w2b)
{
    int i = blockIdx.x * 256 + threadIdx.x;
    const float* in; bf16* out;
    if (i < NX4)              { in = x;  out = xb;  }
    else if (i < NX4 + NW14)  { in = w1; out = w1b; i -= NX4; }
    else                      { in = w2; out = w2b; i -= NX4 + NW14; }
    float4 v = ((const float4*)in)[i];
    bf16x4 o = { (bf16)v.x, (bf16)v.y, (bf16)v.z, (bf16)v.w };
    ((bf16x4*)out)[i] = o;
}

// ---------------------------------------------------------------------------
// C = A * B^T + bias.  128x128 tile, BK=32, 256 threads (m97 structure).
// Columns < qcols additionally scaled by qscale (Q pre-scaling; wave-uniform).
template <int OUT_BF16>
__global__ __launch_bounds__(256) void gemm_bt(const bf16* __restrict__ A,
                                               const bf16* __restrict__ Bw,
                                               const float* __restrict__ bias,
                                               void* __restrict__ Cout,
                                               int M, int N, int K,
                                               float qscale, int qcols)
{
    __shared__ __align__(16) bf16 As[128 * 32];
    __shared__ __align__(16) bf16 Bs[128 * 32];

    const int tid  = threadIdx.x;
    const int wave = tid >> 6, lane = tid & 63;
    const int quad = lane >> 4, l16 = lane & 15;
    const int wm = (wave >> 1) * 64, wn = (wave & 1) * 64;
    const int m0 = blockIdx.x * 128, n0 = blockIdx.y * 128;

    f32x4 acc[4][4] = {};

    const int c0 = tid, c1 = tid + 256;
    const bf16* gA0 = A  + (size_t)(m0 + (c0 >> 2)) * K + (c0 & 3) * 8;
    const bf16* gA1 = A  + (size_t)(m0 + (c1 >> 2)) * K + (c1 & 3) * 8;
    const bf16* gB0 = Bw + (size_t)(n0 + (c0 >> 2)) * K + (c0 & 3) * 8;
    const bf16* gB1 = Bw + (size_t)(n0 + (c1 >> 2)) * K + (c1 & 3) * 8;
    bf16* lA0 = As + c0 * 8;  bf16* lA1 = As + c1 * 8;
    bf16* lB0 = Bs + c0 * 8;  bf16* lB1 = Bs + c1 * 8;

    for (int kb = 0; kb < K; kb += 32) {
        if (kb) __syncthreads();
        load_lds16(gA0 + kb, lA0);
        load_lds16(gA1 + kb, lA1);
        load_lds16(gB0 + kb, lB0);
        load_lds16(gB1 + kb, lB1);
        __syncthreads();

        bf16x8 af[4], bfr[4];
#pragma unroll
        for (int mt = 0; mt < 4; ++mt)
            af[mt] = *(const bf16x8*)(As + (wm + mt * 16 + l16) * 32 + quad * 8);
#pragma unroll
        for (int nt = 0; nt < 4; ++nt)
            bfr[nt] = *(const bf16x8*)(Bs + (wn + nt * 16 + l16) * 32 + quad * 8);
#pragma unroll
        for (int mt = 0; mt < 4; ++mt)
#pragma unroll
            for (int nt = 0; nt < 4; ++nt)
                acc[mt][nt] = MFMA16(af[mt], bfr[nt], acc[mt][nt]);
    }

#pragma unroll
    for (int mt = 0; mt < 4; ++mt)
#pragma unroll
        for (int nt = 0; nt < 4; ++nt) {
            const int row = m0 + wm + mt * 16 + quad * 4;
            const int col = n0 + wn + nt * 16 + l16;
            const float bc = bias[col];
            const float sc = (col < qcols) ? qscale : 1.0f;
#pragma unroll
            for (int r = 0; r < 4; ++r) {
                const float v = (acc[mt][nt][r] + bc) * sc;
                if (OUT_BF16) ((bf16*)Cout)[(size_t)(row + r) * N + col] = (bf16)v;
                else          ((float*)Cout)[(size_t)(row + r) * N + col] = v;
            }
        }
}

// ---------------------------------------------------------------------------
// Vt key-block swizzle keyed on d>>3: conflict-minimal for the packed b32
// transpose-write and the b128 PV read. (round-5-verified)
__device__ __forceinline__ int vswz(int d) { return ((d >> 3) & 7) << 3; }

// Flash attention, S^T formulation — round-5 configuration (64-key tiles,
// 27.6 KB LDS, 2 barriers/iter) + XCD-locality block swizzle:
// all 16 q-tile blocks of one head-batch land on ONE XCD (wg%8 round-robin),
// so each XCD's L2 holds 8 head-batches' K/V (4 MB) instead of streaming all
// 64 from HBM.  Pure index permutation; work/block uniform (33 iters).
__global__ __launch_bounds__(256) void attn_kernel(const bf16* __restrict__ qkv,
                                                   bf16* __restrict__ y)
{
    __shared__ __align__(16) bf16 Ks[64][72];      // [key][d]
    __shared__ __align__(16) bf16 Vt[64][72];      // [d][key ^ vswz(d)]
    __shared__ __align__(16) bf16 Ps[4][16][72];   // per-wave [q=l16][key]

    const int wg = blockIdx.x;
    const int t  = wg & 63;
    const int hb = (t & 7) * 8 + (t >> 3);   // head-batch: constant mod-8 class
    const int p  = wg >> 6;                  // q-tile pair index 0..15
    const int h  = hb & 15;
    const int b  = hb >> 4;

    const int tid  = threadIdx.x;
    const int wave = tid >> 6, lane = tid & 63;
    const int quad = lane >> 4, l16 = lane & 15;

    const bf16* kbase = qkv + (size_t)(b * Ts) * NQKV + DM     + h * HS;
    const bf16* vbase = qkv + (size_t)(b * Ts) * NQKV + 2 * DM + h * HS;

    const int dg = tid & 7, kp = tid >> 3;   // V staging mapping
    const int k0 = 2 * kp;

    for (int phase = 0; phase < 2; ++phase) {
        const int qt = phase ? (31 - p) : p;
        const int qw = qt * 64 + wave * 16;
        const int q_abs = qw + l16;

        const bf16* qrow = qkv + (size_t)(b * Ts + qw + l16) * NQKV + h * HS;
        const bf16x8 qf0 = *(const bf16x8*)(qrow + quad * 8);
        const bf16x8 qf1 = *(const bf16x8*)(qrow + 32 + quad * 8);

        f32x4 o[4] = {};            // O^T[d = dt*16 + quad*4 + r][q = l16]
        float m_run = -1e30f, l_run = 0.f;

        auto iter = [&](int kt, bool masked) {
            __syncthreads();   // prior iter's Ks/Vt reads complete

            // ---- stage K [64x64] natural, b128 writes
            {
                int e = tid * 8;
#pragma unroll
                for (int rr = 0; rr < 2; ++rr, e += 2048) {
                    const int key = e >> 6, c = e & 63;
                    bf16x8 kv = *(const bf16x8*)(kbase + (size_t)(kt * 64 + key) * NQKV + c);
                    *(bf16x8*)&Ks[key][c] = kv;
                }
            }
            // ---- stage V transposed: key-pair packed b32 writes
            {
                const bf16x8 v0 = *(const bf16x8*)(vbase + (size_t)(kt * 64 + k0)     * NQKV + dg * 8);
                const bf16x8 v1 = *(const bf16x8*)(vbase + (size_t)(kt * 64 + k0 + 1) * NQKV + dg * 8);
#pragma unroll
                for (int j = 0; j < 8; ++j) {
                    const int d = dg * 8 + j;
                    *(unsigned int*)&Vt[d][k0 ^ vswz(d)] = pack2(v0[j], v1[j]);
                }
            }
            __syncthreads();

            // ---- S^T (log2 domain, scale pre-folded into Q)
            f32x4 s[4];
#pragma unroll
            for (int sub = 0; sub < 4; ++sub) {
                bf16x8 kf0 = *(const bf16x8*)&Ks[sub * 16 + l16][quad * 8];
                bf16x8 kf1 = *(const bf16x8*)&Ks[sub * 16 + l16][32 + quad * 8];
                f32x4 z = {};
                z = MFMA16(kf0, qf0, z);
                z = MFMA16(kf1, qf1, z);
                s[sub] = z;
            }

            // ---- causal mask: only the diagonal tile needs it
            if (masked) {
#pragma unroll
                for (int sub = 0; sub < 4; ++sub) {
                    const int kb = kt * 64 + sub * 16 + quad * 4;
#pragma unroll
                    for (int r = 0; r < 4; ++r)
                        if (kb + r > q_abs) s[sub][r] = -1e30f;
                }
            }

            // ---- online softmax (log2 domain): balanced trees + 2 shfls
            float mA = fmaxf(fmaxf(s[0][0], s[0][1]), fmaxf(s[0][2], s[0][3]));
            float mB = fmaxf(fmaxf(s[1][0], s[1][1]), fmaxf(s[1][2], s[1][3]));
            float mC = fmaxf(fmaxf(s[2][0], s[2][1]), fmaxf(s[2][2], s[2][3]));
            float mD = fmaxf(fmaxf(s[3][0], s[3][1]), fmaxf(s[3][2], s[3][3]));
            float mx = fmaxf(fmaxf(mA, mB), fmaxf(mC, mD));
            mx = fmaxf(mx, __shfl_xor(mx, 16, 64));
            mx = fmaxf(mx, __shfl_xor(mx, 32, 64));
            const float mnew  = fmaxf(m_run, mx);
            const float alpha = __builtin_amdgcn_exp2f(m_run - mnew);
#pragma unroll
            for (int sub = 0; sub < 4; ++sub)
#pragma unroll
                for (int r = 0; r < 4; ++r)
                    s[sub][r] = __builtin_amdgcn_exp2f(s[sub][r] - mnew);
            float t0 = (s[0][0] + s[0][1]) + (s[0][2] + s[0][3]);
            float t1 = (s[1][0] + s[1][1]) + (s[1][2] + s[1][3]);
            float t2 = (s[2][0] + s[2][1]) + (s[2][2] + s[2][3]);
            float t3 = (s[3][0] + s[3][1]) + (s[3][2] + s[3][3]);
            float ls = (t0 + t1) + (t2 + t3);
            ls += __shfl_xor(ls, 16, 64);
            ls += __shfl_xor(ls, 32, 64);
            l_run = l_run * alpha + ls;
            m_run = mnew;
#pragma unroll
            for (int dt = 0; dt < 4; ++dt)
#pragma unroll
                for (int r = 0; r < 4; ++r) o[dt][r] *= alpha;

            // ---- P -> per-wave LDS [q=l16][key], packed key-pair b32 writes
#pragma unroll
            for (int sub = 0; sub < 4; ++sub) {
                const int kc = sub * 16 + quad * 4;
                *(unsigned int*)&Ps[wave][l16][kc]     = pack2((bf16)s[sub][0], (bf16)s[sub][1]);
                *(unsigned int*)&Ps[wave][l16][kc + 2] = pack2((bf16)s[sub][2], (bf16)s[sub][3]);
            }
            __asm__ volatile("" ::: "memory");   // keep reads below writes

            bf16x8 pb0 = *(const bf16x8*)&Ps[wave][l16][quad * 8];
            bf16x8 pb1 = *(const bf16x8*)&Ps[wave][l16][32 + quad * 8];

            // ---- O^T += V^T * P
#pragma unroll
            for (int kb = 0; kb < 2; ++kb) {
                const int kcol = kb * 32 + quad * 8;
#pragma unroll
                for (int dt = 0; dt < 4; ++dt) {
                    const int d = dt * 16 + l16;
                    bf16x8 vf = *(const bf16x8*)&Vt[d][kcol ^ vswz(d)];
                    o[dt] = MFMA16(vf, kb ? pb1 : pb0, o[dt]);
                }
            }
        };

        for (int kt = 0; kt < qt; ++kt) iter(kt, false);
        iter(qt, true);

        // ---- normalize + write
        const float inv = 1.f / l_run;
        bf16* yrow = y + (size_t)(b * Ts + qw + l16) * DM + h * HS;
#pragma unroll
        for (int dt = 0; dt < 4; ++dt) {
            bf16x4 ov;
#pragma unroll
            for (int r = 0; r < 4; ++r) ov[r] = (bf16)(o[dt][r] * inv);
            *(bf16x4*)(yrow + dt * 16 + quad * 4) = ov;
        }
    }
}

// ---------------------------------------------------------------------------
extern "C" void kernel_launch(void* const* d_in, const int* in_sizes, int n_in,
                              void* d_out, int out_size, void* d_ws, size_t ws_size,
                              hipStream_t stream)
{
    const float* x     = (const float*)d_in[0];
    const float* Wqkv  = (const float*)d_in[1];
    const float* bqkv  = (const float*)d_in[2];
    const float* Wproj = (const float*)d_in[3];
    const float* bproj = (const float*)d_in[4];

    char* ws = (char*)d_ws;
    bf16* xb     = (bf16*)ws;  ws += (size_t)MROWS * DM * 2;
    bf16* wqkvb  = (bf16*)ws;  ws += (size_t)NQKV * DM * 2;
    bf16* wprojb = (bf16*)ws;  ws += (size_t)DM * DM * 2;
    bf16* qkvb   = (bf16*)ws;  ws += (size_t)MROWS * NQKV * 2;
    bf16* yb     = (bf16*)ws;

    cvt3_kernel<<<(NX4 + NW14 + NW24) / 256, 256, 0, stream>>>(
        x, xb, Wqkv, wqkvb, Wproj, wprojb);

    gemm_bt<1><<<dim3(MROWS / 128, NQKV / 128), 256, 0, stream>>>(
        xb, wqkvb, bqkv, qkvb, MROWS, NQKV, DM, QSCALE, DM);

    attn_kernel<<<dim3(16 * NH * Bz), 256, 0, stream>>>(qkvb, yb);

    gemm_bt<0><<<dim3(MROWS / 128, DM / 128), 256, 0, stream>>>(
        yb, wprojb, bproj, d_out, MROWS, DM, DM, 1.0f, 0);
}

// Round 4
// 274.397 us; speedup vs baseline: 1.0893x; 1.0001x over previous
//
#include <hip/hip_runtime.h>
#include <math.h>

typedef __bf16 bf16;
typedef __bf16 bf16x4 __attribute__((ext_vector_type(4)));
typedef __bf16 bf16x8 __attribute__((ext_vector_type(8)));
typedef float  f32x4  __attribute__((ext_vector_type(4)));
typedef unsigned short u16;

#define MFMA16(a, b, c) __builtin_amdgcn_mfma_f32_16x16x32_bf16((a), (b), (c), 0, 0, 0)

constexpr int Bz    = 4;
constexpr int Ts    = 2048;
constexpr int DM    = 1024;
constexpr int NH    = 16;
constexpr int HS    = 64;
constexpr int MROWS = Bz * Ts;   // 8192
constexpr int NQKV  = 3 * DM;    // 3072

// float4-chunk counts for the fused convert kernel
constexpr int NX4  = MROWS * DM / 4;    // 2097152
constexpr int NW14 = NQKV * DM / 4;     //  786432
constexpr int NW24 = DM * DM / 4;       //  262144

// 0.125 (1/sqrt(64)) * log2(e): folded into Q at the QKV-GEMM epilogue.
#define QSCALE 0.18033688011112042f

__device__ __forceinline__ unsigned int pack2(bf16 lo, bf16 hi) {
    return ((unsigned int)__builtin_bit_cast(u16, hi) << 16) |
            (unsigned int)__builtin_bit_cast(u16, lo);
}

// ---------------------------------------------------------------------------
__device__ __forceinline__ void load_lds16(const bf16* g, bf16* l) {
    __builtin_amdgcn_global_load_lds(
        (__attribute__((address_space(1))) void*)(g),
        (__attribute__((address_space(3))) void*)(l), 16, 0, 0);
}

// ---------------------------------------------------------------------------
// Fused fp32->bf16 conversion for x, W_qkv, W_proj in one launch.
// All three ranges are multiples of 256 -> branch is block-uniform.
__global__ __launch_bounds__(256) void cvt3_kernel(const float* __restrict__ x,   bf16* __restrict__ xb,
                                                   const float* __restrict__ w1,  bf16* __restrict__ w1b,
                                                   const float* __restrict__ w2,  bf16* __restrict__ w2b)
{
    int i = blockIdx.x * 256 + threadIdx.x;
    const float* in; bf16* out;
    if (i < NX4)              { in = x;  out = xb;  }
    else if (i < NX4 + NW14)  { in = w1; out = w1b; i -= NX4; }
    else                      { in = w2; out = w2b; i -= NX4 + NW14; }
    float4 v = ((const float4*)in)[i];
    bf16x4 o = { (bf16)v.x, (bf16)v.y, (bf16)v.z, (bf16)v.w };
    ((bf16x4*)out)[i] = o;
}

// ---------------------------------------------------------------------------
// C = A * B^T + bias.  128x128 tile, BK=32, 256 threads (m97 structure).
// Columns < qcols additionally scaled by qscale (Q pre-scaling; wave-uniform).
template <int OUT_BF16>
__global__ __launch_bounds__(256) void gemm_bt(const bf16* __restrict__ A,
                                               const bf16* __restrict__ Bw,
                                               const float* __restrict__ bias,
                                               void* __restrict__ Cout,
                                               int M, int N, int K,
                                               float qscale, int qcols)
{
    __shared__ __align__(16) bf16 As[128 * 32];
    __shared__ __align__(16) bf16 Bs[128 * 32];

    const int tid  = threadIdx.x;
    const int wave = tid >> 6, lane = tid & 63;
    const int quad = lane >> 4, l16 = lane & 15;
    const int wm = (wave >> 1) * 64, wn = (wave & 1) * 64;
    const int m0 = blockIdx.x * 128, n0 = blockIdx.y * 128;

    f32x4 acc[4][4] = {};

    const int c0 = tid, c1 = tid + 256;
    const bf16* gA0 = A  + (size_t)(m0 + (c0 >> 2)) * K + (c0 & 3) * 8;
    const bf16* gA1 = A  + (size_t)(m0 + (c1 >> 2)) * K + (c1 & 3) * 8;
    const bf16* gB0 = Bw + (size_t)(n0 + (c0 >> 2)) * K + (c0 & 3) * 8;
    const bf16* gB1 = Bw + (size_t)(n0 + (c1 >> 2)) * K + (c1 & 3) * 8;
    bf16* lA0 = As + c0 * 8;  bf16* lA1 = As + c1 * 8;
    bf16* lB0 = Bs + c0 * 8;  bf16* lB1 = Bs + c1 * 8;

    for (int kb = 0; kb < K; kb += 32) {
        if (kb) __syncthreads();
        load_lds16(gA0 + kb, lA0);
        load_lds16(gA1 + kb, lA1);
        load_lds16(gB0 + kb, lB0);
        load_lds16(gB1 + kb, lB1);
        __syncthreads();

        bf16x8 af[4], bfr[4];
#pragma unroll
        for (int mt = 0; mt < 4; ++mt)
            af[mt] = *(const bf16x8*)(As + (wm + mt * 16 + l16) * 32 + quad * 8);
#pragma unroll
        for (int nt = 0; nt < 4; ++nt)
            bfr[nt] = *(const bf16x8*)(Bs + (wn + nt * 16 + l16) * 32 + quad * 8);
#pragma unroll
        for (int mt = 0; mt < 4; ++mt)
#pragma unroll
            for (int nt = 0; nt < 4; ++nt)
                acc[mt][nt] = MFMA16(af[mt], bfr[nt], acc[mt][nt]);
    }

#pragma unroll
    for (int mt = 0; mt < 4; ++mt)
#pragma unroll
        for (int nt = 0; nt < 4; ++nt) {
            const int row = m0 + wm + mt * 16 + quad * 4;
            const int col = n0 + wn + nt * 16 + l16;
            const float bc = bias[col];
            const float sc = (col < qcols) ? qscale : 1.0f;
#pragma unroll
            for (int r = 0; r < 4; ++r) {
                const float v = (acc[mt][nt][r] + bc) * sc;
                if (OUT_BF16) ((bf16*)Cout)[(size_t)(row + r) * N + col] = (bf16)v;
                else          ((float*)Cout)[(size_t)(row + r) * N + col] = v;
            }
        }
}

// ---------------------------------------------------------------------------
// Vt key-block swizzle keyed on d>>3: conflict-minimal for the packed b32
// transpose-write and the b128 PV read. (round-5-verified)
__device__ __forceinline__ int vswz(int d) { return ((d >> 3) & 7) << 3; }

// Flash attention, S^T formulation — round-5 configuration (64-key tiles,
// 27.6 KB LDS, 2 barriers/iter, original 3-D grid) + T14 async-STAGE split:
// K/V for tile kt+1 are global-loaded into registers DURING tile kt's compute
// (issued right after the post-stage barrier), and only the LDS writes remain
// between the barriers.  Removes the serial HBM/L2 latency from the
// barrier-to-barrier critical path.  (r3 showed traffic isn't the cost:
// FETCH 254->34 MB moved dur 96.6->106.4; latency exposure is the theory.)
__global__ __launch_bounds__(256) void attn_kernel(const bf16* __restrict__ qkv,
                                                   bf16* __restrict__ y)
{
    __shared__ __align__(16) bf16 Ks[64][72];      // [key][d]
    __shared__ __align__(16) bf16 Vt[64][72];      // [d][key ^ vswz(d)]
    __shared__ __align__(16) bf16 Ps[4][16][72];   // per-wave [q=l16][key]

    const int p = blockIdx.x, h = blockIdx.y, b = blockIdx.z;
    const int tid  = threadIdx.x;
    const int wave = tid >> 6, lane = tid & 63;
    const int quad = lane >> 4, l16 = lane & 15;

    const bf16* kbase = qkv + (size_t)(b * Ts) * NQKV + DM     + h * HS;
    const bf16* vbase = qkv + (size_t)(b * Ts) * NQKV + 2 * DM + h * HS;

    const int dg = tid & 7, kp = tid >> 3;   // staging mapping (K rows kp,kp+32; V keys 2kp,2kp+1)
    const int k0 = 2 * kp;
    const int kc8 = dg * 8;

    // T14 staged registers: K/V of the NEXT tile
    bf16x8 kr0, kr1, vr0, vr1;
    auto load_tile = [&](int kt) {
        const bf16* kb = kbase + (size_t)(kt * 64 + kp) * NQKV + kc8;
        kr0 = *(const bf16x8*)kb;
        kr1 = *(const bf16x8*)(kb + (size_t)32 * NQKV);
        const bf16* vb = vbase + (size_t)(kt * 64 + k0) * NQKV + kc8;
        vr0 = *(const bf16x8*)vb;
        vr1 = *(const bf16x8*)(vb + NQKV);
    };

    for (int phase = 0; phase < 2; ++phase) {
        const int qt = phase ? (31 - p) : p;
        const int qw = qt * 64 + wave * 16;
        const int q_abs = qw + l16;

        const bf16* qrow = qkv + (size_t)(b * Ts + qw + l16) * NQKV + h * HS;
        const bf16x8 qf0 = *(const bf16x8*)(qrow + quad * 8);
        const bf16x8 qf1 = *(const bf16x8*)(qrow + 32 + quad * 8);

        f32x4 o[4] = {};            // O^T[d = dt*16 + quad*4 + r][q = l16]
        float m_run = -1e30f, l_run = 0.f;

        load_tile(0);               // phase prologue: tile 0 into regs

        auto iter = [&](int kt, bool masked) {
            __syncthreads();   // prior iter's Ks/Vt reads complete

            // ---- LDS writes from staged regs (no global latency here)
            *(bf16x8*)&Ks[kp][kc8]      = kr0;
            *(bf16x8*)&Ks[kp + 32][kc8] = kr1;
#pragma unroll
            for (int j = 0; j < 8; ++j) {
                const int d = dg * 8 + j;
                *(unsigned int*)&Vt[d][k0 ^ vswz(d)] = pack2(vr0[j], vr1[j]);
            }
            __syncthreads();

            // ---- prefetch next tile; latency hides under compute below
            if (!masked) load_tile(kt + 1);

            // ---- S^T (log2 domain, scale pre-folded into Q)
            f32x4 s[4];
#pragma unroll
            for (int sub = 0; sub < 4; ++sub) {
                bf16x8 kf0 = *(const bf16x8*)&Ks[sub * 16 + l16][quad * 8];
                bf16x8 kf1 = *(const bf16x8*)&Ks[sub * 16 + l16][32 + quad * 8];
                f32x4 z = {};
                z = MFMA16(kf0, qf0, z);
                z = MFMA16(kf1, qf1, z);
                s[sub] = z;
            }

            // ---- causal mask: only the diagonal tile needs it
            if (masked) {
#pragma unroll
                for (int sub = 0; sub < 4; ++sub) {
                    const int kb = kt * 64 + sub * 16 + quad * 4;
#pragma unroll
                    for (int r = 0; r < 4; ++r)
                        if (kb + r > q_abs) s[sub][r] = -1e30f;
                }
            }

            // ---- online softmax (log2 domain): balanced trees + 2 shfls
            float mA = fmaxf(fmaxf(s[0][0], s[0][1]), fmaxf(s[0][2], s[0][3]));
            float mB = fmaxf(fmaxf(s[1][0], s[1][1]), fmaxf(s[1][2], s[1][3]));
            float mC = fmaxf(fmaxf(s[2][0], s[2][1]), fmaxf(s[2][2], s[2][3]));
            float mD = fmaxf(fmaxf(s[3][0], s[3][1]), fmaxf(s[3][2], s[3][3]));
            float mx = fmaxf(fmaxf(mA, mB), fmaxf(mC, mD));
            mx = fmaxf(mx, __shfl_xor(mx, 16, 64));
            mx = fmaxf(mx, __shfl_xor(mx, 32, 64));
            const float mnew  = fmaxf(m_run, mx);
            const float alpha = __builtin_amdgcn_exp2f(m_run - mnew);
#pragma unroll
            for (int sub = 0; sub < 4; ++sub)
#pragma unroll
                for (int r = 0; r < 4; ++r)
                    s[sub][r] = __builtin_amdgcn_exp2f(s[sub][r] - mnew);
            float t0 = (s[0][0] + s[0][1]) + (s[0][2] + s[0][3]);
            float t1 = (s[1][0] + s[1][1]) + (s[1][2] + s[1][3]);
            float t2 = (s[2][0] + s[2][1]) + (s[2][2] + s[2][3]);
            float t3 = (s[3][0] + s[3][1]) + (s[3][2] + s[3][3]);
            float ls = (t0 + t1) + (t2 + t3);
            ls += __shfl_xor(ls, 16, 64);
            ls += __shfl_xor(ls, 32, 64);
            l_run = l_run * alpha + ls;
            m_run = mnew;
#pragma unroll
            for (int dt = 0; dt < 4; ++dt)
#pragma unroll
                for (int r = 0; r < 4; ++r) o[dt][r] *= alpha;

            // ---- P -> per-wave LDS [q=l16][key], packed key-pair b32 writes
#pragma unroll
            for (int sub = 0; sub < 4; ++sub) {
                const int kc = sub * 16 + quad * 4;
                *(unsigned int*)&Ps[wave][l16][kc]     = pack2((bf16)s[sub][0], (bf16)s[sub][1]);
                *(unsigned int*)&Ps[wave][l16][kc + 2] = pack2((bf16)s[sub][2], (bf16)s[sub][3]);
            }
            __asm__ volatile("" ::: "memory");   // keep reads below writes

            bf16x8 pb0 = *(const bf16x8*)&Ps[wave][l16][quad * 8];
            bf16x8 pb1 = *(const bf16x8*)&Ps[wave][l16][32 + quad * 8];

            // ---- O^T += V^T * P
#pragma unroll
            for (int kb = 0; kb < 2; ++kb) {
                const int kcol = kb * 32 + quad * 8;
#pragma unroll
                for (int dt = 0; dt < 4; ++dt) {
                    const int d = dt * 16 + l16;
                    bf16x8 vf = *(const bf16x8*)&Vt[d][kcol ^ vswz(d)];
                    o[dt] = MFMA16(vf, kb ? pb1 : pb0, o[dt]);
                }
            }
        };

        for (int kt = 0; kt < qt; ++kt) iter(kt, false);
        iter(qt, true);

        // ---- normalize + write
        const float inv = 1.f / l_run;
        bf16* yrow = y + (size_t)(b * Ts + qw + l16) * DM + h * HS;
#pragma unroll
        for (int dt = 0; dt < 4; ++dt) {
            bf16x4 ov;
#pragma unroll
            for (int r = 0; r < 4; ++r) ov[r] = (bf16)(o[dt][r] * inv);
            *(bf16x4*)(yrow + dt * 16 + quad * 4) = ov;
        }
    }
}

// ---------------------------------------------------------------------------
extern "C" void kernel_launch(void* const* d_in, const int* in_sizes, int n_in,
                              void* d_out, int out_size, void* d_ws, size_t ws_size,
                              hipStream_t stream)
{
    const float* x     = (const float*)d_in[0];
    const float* Wqkv  = (const float*)d_in[1];
    const float* bqkv  = (const float*)d_in[2];
    const float* Wproj = (const float*)d_in[3];
    const float* bproj = (const float*)d_in[4];

    char* ws = (char*)d_ws;
    bf16* xb     = (bf16*)ws;  ws += (size_t)MROWS * DM * 2;
    bf16* wqkvb  = (bf16*)ws;  ws += (size_t)NQKV * DM * 2;
    bf16* wprojb = (bf16*)ws;  ws += (size_t)DM * DM * 2;
    bf16* qkvb   = (bf16*)ws;  ws += (size_t)MROWS * NQKV * 2;
    bf16* yb     = (bf16*)ws;

    cvt3_kernel<<<(NX4 + NW14 + NW24) / 256, 256, 0, stream>>>(
        x, xb, Wqkv, wqkvb, Wproj, wprojb);

    gemm_bt<1><<<dim3(MROWS / 128, NQKV / 128), 256, 0, stream>>>(
        xb, wqkvb, bqkv, qkvb, MROWS, NQKV, DM, QSCALE, DM);

    attn_kernel<<<dim3(16, NH, Bz), 256, 0, stream>>>(qkvb, yb);

    gemm_bt<0><<<dim3(MROWS / 128, DM / 128), 256, 0, stream>>>(
        yb, wprojb, bproj, d_out, MROWS, DM, DM, 1.0f, 0);
}